// Round 10
// baseline (103.881 us; speedup 1.0000x reference)
//
#include <hip/hip_runtime.h>
#include <hip/hip_bf16.h>
#include <math.h>

#define B_ 32
#define T_ 128
#define C_ 64
#define E_ 8
#define HID_ 32

__device__ __forceinline__ float sigmoidf_(float x) { return 1.0f / (1.0f + __expf(-x)); }
__device__ __forceinline__ float tanhf_(float x) {
    float xc = fminf(fmaxf(x, -15.0f), 15.0f);
    float e = __expf(2.0f * xc);
    return (e - 1.0f) / (e + 1.0f);
}

// ---------------------------------------------------------------------------
// K0: xp[bt, d] = b_in[d] + x[bt,:] . W_in[d,:]   ('btc,dc->btd')
// grid = B*T, block = 64 (thread = output channel d)
// ---------------------------------------------------------------------------
__global__ __launch_bounds__(64) void k_pre(
    const float* __restrict__ x, const float* __restrict__ W_in, const float* __restrict__ b_in,
    float* __restrict__ xp)
{
    const int bt = blockIdx.x;
    const int tid = threadIdx.x;
    __shared__ __align__(16) float4 xs4[16];
    if (tid < 16) xs4[tid] = ((const float4*)(x + bt * C_))[tid];
    __syncthreads();
    float a = b_in[tid];
    const float4* w4 = (const float4*)(W_in + tid * C_);
#pragma unroll
    for (int k4 = 0; k4 < 16; ++k4) {
        float4 xv = xs4[k4];
        float4 wv = w4[k4];
        a = fmaf(xv.x, wv.x, a); a = fmaf(xv.y, wv.y, a);
        a = fmaf(xv.z, wv.z, a); a = fmaf(xv.w, wv.w, a);
    }
    xp[bt * C_ + tid] = a;
}

// ---------------------------------------------------------------------------
// K1: dense GRU. 8 chains per 64-thread block (all lanes hot).
// Writes hs[chain][t][e] (ws) and fh[chain][e] (ws).
// grid = 256, block = 64.
// ---------------------------------------------------------------------------
__global__ __launch_bounds__(64) void k_gru(
    const float* __restrict__ xp, const float* __restrict__ W_ih, const float* __restrict__ W_hh,
    const float* __restrict__ b_ih, const float* __restrict__ b_hh,
    float* __restrict__ hs, float* __restrict__ fh)
{
    const int tid = threadIdx.x;
    const int ci = tid >> 3;                       // chain-in-block 0..7
    const int e = tid & 7;
    const int chain = blockIdx.x * 8 + ci;         // b*C + c
    const int b = chain >> 6;
    const int c = chain & 63;

    __shared__ float xc[8][T_ + 1];

    // stage this chain's xp column: lane e loads t = e*16 .. e*16+15
    for (int tt = 0; tt < 16; ++tt) {
        const int t = e * 16 + tt;
        xc[ci][t] = xp[(b * T_ + t) * C_ + c];
    }
    __syncthreads();

    float wr[E_], wz[E_], wn[E_];
#pragma unroll
    for (int j = 0; j < E_; ++j) {
        wr[j] = W_hh[(c * 24 + 0 * E_ + e) * E_ + j];
        wz[j] = W_hh[(c * 24 + 1 * E_ + e) * E_ + j];
        wn[j] = W_hh[(c * 24 + 2 * E_ + e) * E_ + j];
    }
    const float wir = W_ih[c * 24 + e], wiz = W_ih[c * 24 + E_ + e], win = W_ih[c * 24 + 2 * E_ + e];
    const float bir = b_ih[c * 24 + e], biz = b_ih[c * 24 + E_ + e], bin_ = b_ih[c * 24 + 2 * E_ + e];
    const float bhr = b_hh[c * 24 + e], bhz = b_hh[c * 24 + E_ + e], bhn = b_hh[c * 24 + 2 * E_ + e];

    float h = 0.0f;
    float* ho = hs + (size_t)chain * T_ * E_ + e;
    for (int t = 0; t < T_; ++t) {
        float xv = xc[ci][t];
        float gr = fmaf(xv, wir, bir) + bhr;
        float gz = fmaf(xv, wiz, biz) + bhz;
        float gn = fmaf(xv, win, bin_);
        float hn = bhn;
#pragma unroll
        for (int j = 0; j < E_; ++j) {
            float hj = __shfl(h, j, E_);
            gr = fmaf(hj, wr[j], gr);
            gz = fmaf(hj, wz[j], gz);
            hn = fmaf(hj, wn[j], hn);
        }
        float r = sigmoidf_(gr);
        float z = sigmoidf_(gz);
        float nn = tanhf_(fmaf(r, hn, gn));
        h = (1.0f - z) * nn + z * h;
        ho[t * E_] = h;
    }
    fh[chain * E_ + e] = h;
}

// ---------------------------------------------------------------------------
// K2: attention per chain (no GRU). grid = B*C, block = 128 (thread = t).
// ---------------------------------------------------------------------------
__global__ __launch_bounds__(128) void k_attn(
    const float* __restrict__ hs, const float* __restrict__ W_qkv, const float* __restrict__ b_qkv,
    const float* __restrict__ W_o, const float* __restrict__ b_o,
    float* __restrict__ feat_imp, float* __restrict__ tsf_imp)
{
    const int bc = blockIdx.x;
    const int b = bc >> 6, c = bc & 63;
    const int t = threadIdx.x;

    __shared__ __align__(16) float ks[T_][E_];
    __shared__ __align__(16) float vs[T_][E_];
    __shared__ float red[T_];

    // coalesced 32B/thread load of this t's hidden row
    float hrow[E_];
    {
        const float4* hp = (const float4*)(hs + (size_t)bc * T_ * E_ + t * E_);
        float4 h0 = hp[0], h1 = hp[1];
        hrow[0] = h0.x; hrow[1] = h0.y; hrow[2] = h0.z; hrow[3] = h0.w;
        hrow[4] = h1.x; hrow[5] = h1.y; hrow[6] = h1.z; hrow[7] = h1.w;
    }

    // q (pre-scaled by 1/sqrt(D)*log2(e) for exp2), k, v
    const float qscale = 0.70710678118654752f * 1.44269504088896341f;
    float q[E_];
#pragma unroll
    for (int f = 0; f < E_; ++f) {
        float a = b_qkv[f];
#pragma unroll
        for (int j = 0; j < E_; ++j) a = fmaf(hrow[j], W_qkv[f * E_ + j], a);
        q[f] = a * qscale;
    }
#pragma unroll
    for (int f = 0; f < E_; ++f) {
        float a = b_qkv[E_ + f];
#pragma unroll
        for (int j = 0; j < E_; ++j) a = fmaf(hrow[j], W_qkv[(E_ + f) * E_ + j], a);
        ks[t][f] = a;
    }
#pragma unroll
    for (int f = 0; f < E_; ++f) {
        float a = b_qkv[2 * E_ + f];
#pragma unroll
        for (int j = 0; j < E_; ++j) a = fmaf(hrow[j], W_qkv[(2 * E_ + f) * E_ + j], a);
        vs[t][f] = a;
    }
    __syncthreads();

    // online (un-maxed) softmax accumulation; exp2 with prescaled q
    float l[4] = {0.f, 0.f, 0.f, 0.f};
    float acc[E_] = {0.f, 0.f, 0.f, 0.f, 0.f, 0.f, 0.f, 0.f};
    for (int s = 0; s < T_; ++s) {
        float4 k0 = *(const float4*)&ks[s][0];
        float4 k1 = *(const float4*)&ks[s][4];
        float4 v0 = *(const float4*)&vs[s][0];
        float4 v1 = *(const float4*)&vs[s][4];
        float p0 = exp2f(fmaf(q[1], k0.y, q[0] * k0.x));
        float p1 = exp2f(fmaf(q[3], k0.w, q[2] * k0.z));
        float p2 = exp2f(fmaf(q[5], k1.y, q[4] * k1.x));
        float p3 = exp2f(fmaf(q[7], k1.w, q[6] * k1.z));
        l[0] += p0; l[1] += p1; l[2] += p2; l[3] += p3;
        acc[0] = fmaf(p0, v0.x, acc[0]); acc[1] = fmaf(p0, v0.y, acc[1]);
        acc[2] = fmaf(p1, v0.z, acc[2]); acc[3] = fmaf(p1, v0.w, acc[3]);
        acc[4] = fmaf(p2, v1.x, acc[4]); acc[5] = fmaf(p2, v1.y, acc[5]);
        acc[6] = fmaf(p3, v1.z, acc[6]); acc[7] = fmaf(p3, v1.w, acc[7]);
    }

    // S = sum_f attn_out[t,f]
    float S = 0.0f;
#pragma unroll
    for (int f = 0; f < E_; ++f) {
        float wsum = 0.0f;
#pragma unroll
        for (int fp = 0; fp < E_; ++fp) wsum += W_o[fp * E_ + f];
        S = fmaf(acc[f] / l[f >> 1], wsum, S);
    }
#pragma unroll
    for (int fp = 0; fp < E_; ++fp) S += b_o[fp];

    tsf_imp[(size_t)b * T_ * C_ + (size_t)t * C_ + c] = sigmoidf_(S);

    red[t] = S;
    __syncthreads();
    for (int off = 64; off > 0; off >>= 1) {
        if (t < off) red[t] += red[t + off];
        __syncthreads();
    }
    if (t == 0) feat_imp[bc] = sigmoidf_(red[0]);
}

// ---------------------------------------------------------------------------
// K3: ts_imp. grid = B*T, block = 64.
// ---------------------------------------------------------------------------
__global__ __launch_bounds__(64) void k_ts(
    const float* __restrict__ x,
    const float* __restrict__ W_ts1, const float* __restrict__ b_ts1,
    const float* __restrict__ W_ts2, const float* __restrict__ b_ts2,
    float* __restrict__ ts_imp)
{
    const int bt = blockIdx.x;
    const int tid = threadIdx.x;
    __shared__ float xs[C_];
    __shared__ float h1[16];
    xs[tid] = x[bt * C_ + tid];
    __syncthreads();
    if (tid < 16) {
        float a = b_ts1[tid];
#pragma unroll
        for (int k = 0; k < C_; ++k) a = fmaf(xs[k], W_ts1[tid * C_ + k], a);
        h1[tid] = 0.5f * a * (1.0f + erff(a * 0.70710678118654752f));
    }
    __syncthreads();
    if (tid == 0) {
        float s = b_ts2[0];
#pragma unroll
        for (int k = 0; k < 16; ++k) s = fmaf(h1[k], W_ts2[k], s);
        ts_imp[bt] = sigmoidf_(s);
    }
}

// ---------------------------------------------------------------------------
// K4: out0[b,o] = b_out[o] + sum_k fh[b*C..][k] * W_out[o,k]
// grid = B, block = 64.
// ---------------------------------------------------------------------------
__global__ __launch_bounds__(64) void k_out(
    const float* __restrict__ fh, const float* __restrict__ W_out, const float* __restrict__ b_out,
    float* __restrict__ out0)
{
    const int b = blockIdx.x;
    const int tid = threadIdx.x;
    __shared__ float hf[C_ * E_];
    const float4* src = (const float4*)(fh + (b * C_ + tid) * E_);
    float4* dst = (float4*)(hf + tid * E_);
    dst[0] = src[0];
    dst[1] = src[1];
    __syncthreads();
    if (tid < HID_) {
        float a = b_out[tid];
        const float* wo = W_out + tid * (C_ * E_);
        for (int k = 0; k < C_ * E_; ++k) a = fmaf(hf[k], wo[k], a);
        out0[b * HID_ + tid] = a;
    }
}

// ---------------------------------------------------------------------------
extern "C" void kernel_launch(void* const* d_in, const int* in_sizes, int n_in,
                              void* d_out, int out_size, void* d_ws, size_t ws_size,
                              hipStream_t stream) {
    (void)in_sizes; (void)n_in; (void)out_size; (void)ws_size;

    // outputs are FLOAT32, concatenated in return order
    float* out0 = (float*)d_out;                 // (B, HID)    1024
    float* feat = out0 + B_ * HID_;              // (B, C)      2048
    float* tsim = feat + B_ * C_;                // (B, T)      4096
    float* tsf  = tsim + B_ * T_;                // (B, T, C) 262144

    const float* x     = (const float*)d_in[0];
    const float* W_in  = (const float*)d_in[1];
    const float* b_in  = (const float*)d_in[2];
    const float* W_ts1 = (const float*)d_in[3];
    const float* b_ts1 = (const float*)d_in[4];
    const float* W_ts2 = (const float*)d_in[5];
    const float* b_ts2 = (const float*)d_in[6];
    const float* W_ih  = (const float*)d_in[7];
    const float* W_hh  = (const float*)d_in[8];
    const float* b_ih  = (const float*)d_in[9];
    const float* b_hh  = (const float*)d_in[10];
    const float* W_qkv = (const float*)d_in[11];
    const float* b_qkv = (const float*)d_in[12];
    const float* W_o   = (const float*)d_in[13];
    const float* b_o   = (const float*)d_in[14];
    const float* W_out = (const float*)d_in[15];
    const float* b_out = (const float*)d_in[16];

    // ws layout (f32): fh (16K) | xp (256K) | hs (2M)
    float* fhb = (float*)d_ws;
    float* xpb = fhb + B_ * C_ * E_;
    float* hsb = xpb + (size_t)B_ * T_ * C_;

    hipLaunchKernelGGL(k_pre, dim3(B_ * T_), dim3(64), 0, stream, x, W_in, b_in, xpb);
    hipLaunchKernelGGL(k_gru, dim3(B_ * C_ / 8), dim3(64), 0, stream,
                       xpb, W_ih, W_hh, b_ih, b_hh, hsb, fhb);
    hipLaunchKernelGGL(k_attn, dim3(B_ * C_), dim3(128), 0, stream,
                       hsb, W_qkv, b_qkv, W_o, b_o, feat, tsf);
    hipLaunchKernelGGL(k_ts, dim3(B_ * T_), dim3(64), 0, stream,
                       x, W_ts1, b_ts1, W_ts2, b_ts2, tsim);
    hipLaunchKernelGGL(k_out, dim3(B_), dim3(64), 0, stream,
                       fhb, W_out, b_out, out0);
}

// Round 11
// 101.750 us; speedup vs baseline: 1.0209x; 1.0209x over previous
//
#include <hip/hip_runtime.h>
#include <hip/hip_bf16.h>
#include <math.h>

#define B_ 32
#define T_ 128
#define C_ 64
#define E_ 8
#define HID_ 32

__device__ __forceinline__ float sigmoidf_(float x) { return 1.0f / (1.0f + __expf(-x)); }
__device__ __forceinline__ float tanhf_(float x) {
    float xc = fminf(fmaxf(x, -15.0f), 15.0f);
    float e = __expf(2.0f * xc);
    return (e - 1.0f) / (e + 1.0f);
}

// ---------------------------------------------------------------------------
// K1: GRU with inline xp. 8 chains per 64-thread block (all lanes hot).
// Per chain: xcol[t] = b_in[c] + x[b,t,:].W_in[c,:], then the 128-step scan.
// Writes hs[chain][t][e] and fh[chain][e] to ws. grid = 256, block = 64.
// ---------------------------------------------------------------------------
__global__ __launch_bounds__(64) void k_gru(
    const float* __restrict__ x, const float* __restrict__ W_in, const float* __restrict__ b_in,
    const float* __restrict__ W_ih, const float* __restrict__ W_hh,
    const float* __restrict__ b_ih, const float* __restrict__ b_hh,
    float* __restrict__ hs, float* __restrict__ fh)
{
    const int tid = threadIdx.x;
    const int ci = tid >> 3;                       // chain-in-block 0..7
    const int e = tid & 7;
    const int chain = blockIdx.x * 8 + ci;         // b*C + c  (8 chains share b)
    const int b = chain >> 6;
    const int c = chain & 63;

    __shared__ float wsh[8][C_];                   // W_in rows for the 8 chains
    __shared__ float xc[8][T_ + 1];

    // stage W_in rows: 512 floats, 8 per thread
#pragma unroll
    for (int i = 0; i < 8; ++i) {
        int idx = tid * 8 + i;                     // 0..511
        int ci2 = idx >> 6;
        int cc = (blockIdx.x * 8 + ci2) & 63;
        wsh[ci2][idx & 63] = W_in[cc * C_ + (idx & 63)];
    }
    __syncthreads();

    // xcol: lane e computes t = e*16 .. e*16+15 (x via float4, w via LDS bcast)
    const float bi = b_in[c];
    for (int tt = 0; tt < 16; ++tt) {
        const int t = e * 16 + tt;
        const float4* xr = (const float4*)(x + (b * T_ + t) * C_);
        float a = bi;
#pragma unroll
        for (int k4 = 0; k4 < 16; ++k4) {
            float4 xv = xr[k4];
            a = fmaf(xv.x, wsh[ci][k4 * 4 + 0], a);
            a = fmaf(xv.y, wsh[ci][k4 * 4 + 1], a);
            a = fmaf(xv.z, wsh[ci][k4 * 4 + 2], a);
            a = fmaf(xv.w, wsh[ci][k4 * 4 + 3], a);
        }
        xc[ci][t] = a;
    }
    __syncthreads();

    float wr[E_], wz[E_], wn[E_];
#pragma unroll
    for (int j = 0; j < E_; ++j) {
        wr[j] = W_hh[(c * 24 + 0 * E_ + e) * E_ + j];
        wz[j] = W_hh[(c * 24 + 1 * E_ + e) * E_ + j];
        wn[j] = W_hh[(c * 24 + 2 * E_ + e) * E_ + j];
    }
    const float wir = W_ih[c * 24 + e], wiz = W_ih[c * 24 + E_ + e], win = W_ih[c * 24 + 2 * E_ + e];
    const float bir = b_ih[c * 24 + e], biz = b_ih[c * 24 + E_ + e], bin_ = b_ih[c * 24 + 2 * E_ + e];
    const float bhr = b_hh[c * 24 + e], bhz = b_hh[c * 24 + E_ + e], bhn = b_hh[c * 24 + 2 * E_ + e];

    float h = 0.0f;
    float* ho = hs + (size_t)chain * T_ * E_ + e;
    for (int t = 0; t < T_; ++t) {
        float xv = xc[ci][t];
        float gr = fmaf(xv, wir, bir) + bhr;
        float gz = fmaf(xv, wiz, biz) + bhz;
        float gn = fmaf(xv, win, bin_);
        float hn = bhn;
#pragma unroll
        for (int j = 0; j < E_; ++j) {
            float hj = __shfl(h, j, E_);
            gr = fmaf(hj, wr[j], gr);
            gz = fmaf(hj, wz[j], gz);
            hn = fmaf(hj, wn[j], hn);
        }
        float r = sigmoidf_(gr);
        float z = sigmoidf_(gz);
        float nn = tanhf_(fmaf(r, hn, gn));
        h = (1.0f - z) * nn + z * h;
        ho[t * E_] = h;
    }
    fh[chain * E_ + e] = h;
}

// ---------------------------------------------------------------------------
// K2: attention per chain, 2-way s-split. grid = B*C, block = 256.
// thread (t = tid&127, p = tid>>7); p covers s in [p*64, p*64+64).
// ---------------------------------------------------------------------------
__global__ __launch_bounds__(256) void k_attn(
    const float* __restrict__ hs, const float* __restrict__ W_qkv, const float* __restrict__ b_qkv,
    const float* __restrict__ W_o, const float* __restrict__ b_o,
    float* __restrict__ feat_imp, float* __restrict__ tsf_imp)
{
    const int bc = blockIdx.x;
    const int b = bc >> 6, c = bc & 63;
    const int tid = threadIdx.x;
    const int t = tid & 127;
    const int p = tid >> 7;

    __shared__ __align__(16) float ks[T_][E_];
    __shared__ __align__(16) float vs[T_][E_];
    __shared__ __align__(16) float pacc[T_][12];   // p=1 partials: l[4], acc[8]
    __shared__ float wssum[E_];
    __shared__ float bsum_s;
    __shared__ float red[T_];

    // hidden row (both halves load; coalesced, L2-hot)
    float hrow[E_];
    {
        const float4* hp = (const float4*)(hs + (size_t)bc * T_ * E_ + t * E_);
        float4 h0 = hp[0], h1 = hp[1];
        hrow[0] = h0.x; hrow[1] = h0.y; hrow[2] = h0.z; hrow[3] = h0.w;
        hrow[4] = h1.x; hrow[5] = h1.y; hrow[6] = h1.z; hrow[7] = h1.w;
    }

    // q (both, pre-scaled for exp2); k by p=0; v by p=1
    const float qscale = 0.70710678118654752f * 1.44269504088896341f;
    float q[E_];
#pragma unroll
    for (int f = 0; f < E_; ++f) {
        float a = b_qkv[f];
#pragma unroll
        for (int j = 0; j < E_; ++j) a = fmaf(hrow[j], W_qkv[f * E_ + j], a);
        q[f] = a * qscale;
    }
    if (p == 0) {
#pragma unroll
        for (int f = 0; f < E_; ++f) {
            float a = b_qkv[E_ + f];
#pragma unroll
            for (int j = 0; j < E_; ++j) a = fmaf(hrow[j], W_qkv[(E_ + f) * E_ + j], a);
            ks[t][f] = a;
        }
    } else {
#pragma unroll
        for (int f = 0; f < E_; ++f) {
            float a = b_qkv[2 * E_ + f];
#pragma unroll
            for (int j = 0; j < E_; ++j) a = fmaf(hrow[j], W_qkv[(2 * E_ + f) * E_ + j], a);
            vs[t][f] = a;
        }
    }
    if (tid < E_) {                       // W_o column sums (once per block)
        float ws = 0.0f;
#pragma unroll
        for (int fp = 0; fp < E_; ++fp) ws += W_o[fp * E_ + tid];
        wssum[tid] = ws;
    }
    if (tid == E_) {
        float bs = 0.0f;
#pragma unroll
        for (int fp = 0; fp < E_; ++fp) bs += b_o[fp];
        bsum_s = bs;
    }
    __syncthreads();

    // each thread: 64 s values of its row
    float l[4] = {0.f, 0.f, 0.f, 0.f};
    float acc[E_] = {0.f, 0.f, 0.f, 0.f, 0.f, 0.f, 0.f, 0.f};
    const int s0 = p * 64;
    for (int s = s0; s < s0 + 64; ++s) {
        float4 k0 = *(const float4*)&ks[s][0];
        float4 k1 = *(const float4*)&ks[s][4];
        float4 v0 = *(const float4*)&vs[s][0];
        float4 v1 = *(const float4*)&vs[s][4];
        float p0 = exp2f(fmaf(q[1], k0.y, q[0] * k0.x));
        float p1 = exp2f(fmaf(q[3], k0.w, q[2] * k0.z));
        float p2 = exp2f(fmaf(q[5], k1.y, q[4] * k1.x));
        float p3 = exp2f(fmaf(q[7], k1.w, q[6] * k1.z));
        l[0] += p0; l[1] += p1; l[2] += p2; l[3] += p3;
        acc[0] = fmaf(p0, v0.x, acc[0]); acc[1] = fmaf(p0, v0.y, acc[1]);
        acc[2] = fmaf(p1, v0.z, acc[2]); acc[3] = fmaf(p1, v0.w, acc[3]);
        acc[4] = fmaf(p2, v1.x, acc[4]); acc[5] = fmaf(p2, v1.y, acc[5]);
        acc[6] = fmaf(p3, v1.z, acc[6]); acc[7] = fmaf(p3, v1.w, acc[7]);
    }

    if (p == 1) {
#pragma unroll
        for (int i = 0; i < 4; ++i) pacc[t][i] = l[i];
#pragma unroll
        for (int j = 0; j < 8; ++j) pacc[t][4 + j] = acc[j];
    }
    __syncthreads();

    if (p == 0) {
#pragma unroll
        for (int i = 0; i < 4; ++i) l[i] += pacc[t][i];
#pragma unroll
        for (int j = 0; j < 8; ++j) acc[j] += pacc[t][4 + j];
        float S = bsum_s;
#pragma unroll
        for (int f = 0; f < E_; ++f) S = fmaf(acc[f] / l[f >> 1], wssum[f], S);
        tsf_imp[(size_t)b * T_ * C_ + (size_t)t * C_ + c] = sigmoidf_(S);
        red[t] = S;
    }
    __syncthreads();
    for (int off = 64; off > 0; off >>= 1) {
        if (p == 0 && t < off) red[t] += red[t + off];
        __syncthreads();
    }
    if (tid == 0) feat_imp[bc] = sigmoidf_(red[0]);
}

// ---------------------------------------------------------------------------
// K3: ts_imp. grid = B*T, block = 64.
// ---------------------------------------------------------------------------
__global__ __launch_bounds__(64) void k_ts(
    const float* __restrict__ x,
    const float* __restrict__ W_ts1, const float* __restrict__ b_ts1,
    const float* __restrict__ W_ts2, const float* __restrict__ b_ts2,
    float* __restrict__ ts_imp)
{
    const int bt = blockIdx.x;
    const int tid = threadIdx.x;
    __shared__ float xs[C_];
    __shared__ float h1[16];
    xs[tid] = x[bt * C_ + tid];
    __syncthreads();
    if (tid < 16) {
        float a = b_ts1[tid];
#pragma unroll
        for (int k = 0; k < C_; ++k) a = fmaf(xs[k], W_ts1[tid * C_ + k], a);
        h1[tid] = 0.5f * a * (1.0f + erff(a * 0.70710678118654752f));
    }
    __syncthreads();
    if (tid == 0) {
        float s = b_ts2[0];
#pragma unroll
        for (int k = 0; k < 16; ++k) s = fmaf(h1[k], W_ts2[k], s);
        ts_imp[bt] = sigmoidf_(s);
    }
}

// ---------------------------------------------------------------------------
// K4: out0[b,o] = b_out[o] + sum_k fh[b*C..][k] * W_out[o,k]. grid = B.
// ---------------------------------------------------------------------------
__global__ __launch_bounds__(64) void k_out(
    const float* __restrict__ fh, const float* __restrict__ W_out, const float* __restrict__ b_out,
    float* __restrict__ out0)
{
    const int b = blockIdx.x;
    const int tid = threadIdx.x;
    __shared__ float hf[C_ * E_];
    const float4* src = (const float4*)(fh + (b * C_ + tid) * E_);
    float4* dst = (float4*)(hf + tid * E_);
    dst[0] = src[0];
    dst[1] = src[1];
    __syncthreads();
    if (tid < HID_) {
        float a = b_out[tid];
        const float* wo = W_out + tid * (C_ * E_);
        for (int k = 0; k < C_ * E_; ++k) a = fmaf(hf[k], wo[k], a);
        out0[b * HID_ + tid] = a;
    }
}

// ---------------------------------------------------------------------------
extern "C" void kernel_launch(void* const* d_in, const int* in_sizes, int n_in,
                              void* d_out, int out_size, void* d_ws, size_t ws_size,
                              hipStream_t stream) {
    (void)in_sizes; (void)n_in; (void)out_size; (void)ws_size;

    // outputs are FLOAT32, concatenated in return order
    float* out0 = (float*)d_out;                 // (B, HID)    1024
    float* feat = out0 + B_ * HID_;              // (B, C)      2048
    float* tsim = feat + B_ * C_;                // (B, T)      4096
    float* tsf  = tsim + B_ * T_;                // (B, T, C) 262144

    const float* x     = (const float*)d_in[0];
    const float* W_in  = (const float*)d_in[1];
    const float* b_in  = (const float*)d_in[2];
    const float* W_ts1 = (const float*)d_in[3];
    const float* b_ts1 = (const float*)d_in[4];
    const float* W_ts2 = (const float*)d_in[5];
    const float* b_ts2 = (const float*)d_in[6];
    const float* W_ih  = (const float*)d_in[7];
    const float* W_hh  = (const float*)d_in[8];
    const float* b_ih  = (const float*)d_in[9];
    const float* b_hh  = (const float*)d_in[10];
    const float* W_qkv = (const float*)d_in[11];
    const float* b_qkv = (const float*)d_in[12];
    const float* W_o   = (const float*)d_in[13];
    const float* b_o   = (const float*)d_in[14];
    const float* W_out = (const float*)d_in[15];
    const float* b_out = (const float*)d_in[16];

    // ws layout (f32): fh (16K) | hs (8M)
    float* fhb = (float*)d_ws;
    float* hsb = fhb + B_ * C_ * E_;

    hipLaunchKernelGGL(k_gru, dim3(B_ * C_ / 8), dim3(64), 0, stream,
                       x, W_in, b_in, W_ih, W_hh, b_ih, b_hh, hsb, fhb);
    hipLaunchKernelGGL(k_attn, dim3(B_ * C_), dim3(256), 0, stream,
                       hsb, W_qkv, b_qkv, W_o, b_o, feat, tsf);
    hipLaunchKernelGGL(k_ts, dim3(B_ * T_), dim3(64), 0, stream,
                       x, W_ts1, b_ts1, W_ts2, b_ts2, tsim);
    hipLaunchKernelGGL(k_out, dim3(B_), dim3(64), 0, stream,
                       fhb, W_out, b_out, out0);
}